// Round 10
// baseline (34.386 us; speedup 1.0000x reference)
//
#include <hip/hip_runtime.h>
#include <math.h>

#define NROWS 8192
#define DD    64
#define NBLK  256                      // == CU count; all blocks co-resident
#define TPB   512                      // 8 waves/block
#define WPB   8
#define RPW   (NROWS / (NBLK * WPB))   // 4 rows per wave
#define CHUNK (NBLK / WPB)             // 32 partials combined per wave
#define MAGIC 0x9E3779B97F4A7C15ull    // != 0xAAAA.. poison, != 0 (post-run state)

// CDNA spin idiom (R8/R9 post-mortem): plain/relaxed loads can hit a stale
// never-invalidated copy in the spinner's own XCD L2 (waits for natural
// eviction, ~20us); acquire-per-poll invalidates L1+L2 every iteration
// (also ~20us). Atomic RMWs execute at the coherence point: always fresh,
// invalidate nothing. So ALL sync-var reads AND writes are RMWs
// (atomicAdd(p,0) to read, atomicExch to write).

// Star-graph GAT, both layers in ONE dispatch (identities validated r1-r9, absmax 3.9e-3):
//   e[i][j] = h1[i] + h2[j]; h1 cancels in row softmax -> s[j] = h[j]·A[:64]
//   row i>0: masked softmax = 2-way {j=0, j=i};  row 0: full softmax via partials
//   exp without max-subtraction safe in fp32 (|s| <~ 8)
// Layer-1 rows live in registers only. Cross-block: layer-1 row 0 (barrier +
// redundant fixed-order combine) and final out[0] (last-block-done).
// Protocol: block0 exch-zeroes counters, fence, exch-publishes flag=MAGIC;
// blocks RMW-spin on flag, fence, arrive at cnt[0], RMW-spin to NBLK, fence.
// Unique last cnt[1] arriver (old==NBLK-1) writes out[0], exch-resets state to
// zeros (next replay starts clean; post-poison replay sees 0xAA.. != MAGIC).
__global__ __launch_bounds__(TPB) void gat_fused_k(
    const float* __restrict__ x, const float* __restrict__ A1,
    const float* __restrict__ A2, float* __restrict__ out,
    float* __restrict__ part1, float* __restrict__ z1,
    float* __restrict__ part2, float* __restrict__ z2,
    unsigned long long* __restrict__ flag, unsigned int* __restrict__ cnt)
{
    const int lane = threadIdx.x & 63;
    const int wl   = threadIdx.x >> 6;
    const int r0   = (blockIdx.x * WPB + wl) * RPW;

    __shared__ float sacc[WPB][DD];
    __shared__ float sz[WPB];
    __shared__ int amLast;

    if (blockIdx.x == 0 && threadIdx.x == 0) {
        atomicExch(&cnt[0], 0u);        // RMW: coherent, no stale dirty copy
        atomicExch(&cnt[1], 0u);
        __threadfence();
        atomicExch(flag, MAGIC);        // publish zeroed counters
    }

    // ---------------- phase A: layer 1 (rows in registers) ----------------
    float w1 = A1[lane];
    float x0 = x[lane];                 // row 0, lane-distributed
    float v0 = x0 * w1;
    #pragma unroll
    for (int o = 32; o; o >>= 1) v0 += __shfl_xor(v0, o);
    float e0 = expf(v0);

    float o1[RPW];                      // this wave's layer-1 outputs (never stored)
    float acc = 0.f, z = 0.f;
    #pragma unroll
    for (int k = 0; k < RPW; ++k) {
        int r = r0 + k;
        float hv = x[r * DD + lane];
        float t = hv * w1;
        #pragma unroll
        for (int o = 32; o; o >>= 1) t += __shfl_xor(t, o);
        float e = expf(t);
        acc += e * hv;                  // row-0 weighted-sum partial (incl. r=0)
        z   += e;
        o1[k] = (e0 * x0 + e * hv) / (e0 + e);  // 2-way softmax; r==0 slot unused
    }
    sacc[wl][lane] = acc;
    if (lane == 0) sz[wl] = z;
    __syncthreads();
    if (wl == 0) {
        float p = 0.f;
        #pragma unroll
        for (int j = 0; j < WPB; ++j) p += sacc[j][lane];
        part1[blockIdx.x * DD + lane] = p;
        if (lane == 0) {
            float zs = 0.f;
            #pragma unroll
            for (int j = 0; j < WPB; ++j) zs += sz[j];
            z1[blockIdx.x] = zs;
        }
    }
    __syncthreads();                    // part1/z1 stores issued block-wide

    // ------------- device barrier: RMW polls (coherence-point reads) -------------
    if (threadIdx.x == 0) {
        while (atomicAdd(flag, 0ull) != MAGIC) __builtin_amdgcn_s_sleep(32);
        __threadfence();                // release this block's part1/z1
        atomicAdd(&cnt[0], 1u);
        while (atomicAdd(&cnt[0], 0u) < NBLK) __builtin_amdgcn_s_sleep(32);
        __threadfence();                // one acquire: part1/z1 fresh for this CU
    }
    __syncthreads();

    // ---------------- phase B: redundant fixed-order combine -> h1[0] ----------------
    float a = 0.f;
    #pragma unroll
    for (int i = 0; i < CHUNK; ++i) a += part1[(wl * CHUNK + i) * DD + lane];
    float zz = (lane < CHUNK) ? z1[wl * CHUNK + lane] : 0.f;
    #pragma unroll
    for (int o = 32; o; o >>= 1) zz += __shfl_xor(zz, o);
    sacc[wl][lane] = a;
    if (lane == 0) sz[wl] = zz;
    __syncthreads();
    float P = 0.f, Z = 0.f;
    #pragma unroll
    for (int j = 0; j < WPB; ++j) P += sacc[j][lane];
    #pragma unroll
    for (int j = 0; j < WPB; ++j) Z += sz[j];
    float h0 = P / Z;                   // layer-1 out[0], lane-distributed

    // ---------------- phase C: layer 2 from registers ----------------
    float w2 = A2[lane];
    float v02 = h0 * w2;
    #pragma unroll
    for (int o = 32; o; o >>= 1) v02 += __shfl_xor(v02, o);
    float e02 = expf(v02);

    acc = 0.f; z = 0.f;
    #pragma unroll
    for (int k = 0; k < RPW; ++k) {
        int r = r0 + k;
        float hv = (r == 0) ? h0 : o1[k];
        float t = hv * w2;
        #pragma unroll
        for (int o = 32; o; o >>= 1) t += __shfl_xor(t, o);
        float e = expf(t);
        acc += e * hv;
        z   += e;
        if (r != 0) {
            float inv = 1.f / (e02 + e);
            out[r * DD + lane] = (e02 * h0 + e * hv) * inv;
        }
    }
    __syncthreads();                    // phase-B sacc/sz reads done before rewrite
    sacc[wl][lane] = acc;
    if (lane == 0) sz[wl] = z;
    __syncthreads();
    if (wl == 0) {
        float p = 0.f;
        #pragma unroll
        for (int j = 0; j < WPB; ++j) p += sacc[j][lane];
        part2[blockIdx.x * DD + lane] = p;
        if (lane == 0) {
            float zs = 0.f;
            #pragma unroll
            for (int j = 0; j < WPB; ++j) zs += sz[j];
            z2[blockIdx.x] = zs;
        }
    }
    __syncthreads();

    // ---------------- last-block-done: final out[0] + state reset ----------------
    if (threadIdx.x == 0) {
        __threadfence();                // release part2/z2 stores
        unsigned old = atomicAdd(&cnt[1], 1u);
        amLast = (old == NBLK - 1) ? 1 : 0;   // unique last block
    }
    __syncthreads();

    if (amLast) {
        __threadfence();                // acquire
        float a2 = 0.f;
        #pragma unroll
        for (int i = 0; i < CHUNK; ++i) a2 += part2[(wl * CHUNK + i) * DD + lane];
        float zz2 = (lane < CHUNK) ? z2[wl * CHUNK + lane] : 0.f;
        #pragma unroll
        for (int o = 32; o; o >>= 1) zz2 += __shfl_xor(zz2, o);
        sacc[wl][lane] = a2;
        if (lane == 0) sz[wl] = zz2;
        __syncthreads();
        if (wl == 0) {
            float P2 = 0.f, Z2 = 0.f;
            #pragma unroll
            for (int j = 0; j < WPB; ++j) P2 += sacc[j][lane];
            #pragma unroll
            for (int j = 0; j < WPB; ++j) Z2 += sz[j];
            out[lane] = P2 / Z2;        // fixed order -> deterministic
        }
        if (threadIdx.x == 0) {         // canonical post-run state: all zeros (RMW)
            atomicExch(&cnt[0], 0u);
            atomicExch(&cnt[1], 0u);
            __threadfence();
            atomicExch(flag, 0ull);
        }
    }
}

extern "C" void kernel_launch(void* const* d_in, const int* in_sizes, int n_in,
                              void* d_out, int out_size, void* d_ws, size_t ws_size,
                              hipStream_t stream)
{
    const float* x  = (const float*)d_in[0];
    const float* A1 = (const float*)d_in[1];
    const float* A2 = (const float*)d_in[2];
    float* out = (float*)d_out;
    float* ws  = (float*)d_ws;

    float* part1 = ws;                          // 256*64
    float* z1    = part1 + NBLK * DD;           // 256
    float* part2 = z1 + NBLK;                   // 256*64
    float* z2    = part2 + NBLK * DD;           // 256
    unsigned long long* flag = (unsigned long long*)(z2 + NBLK);  // 8B-aligned
    unsigned int* cnt = (unsigned int*)(flag + 1);                // 2 uints

    gat_fused_k<<<NBLK, TPB, 0, stream>>>(x, A1, A2, out, part1, z1,
                                          part2, z2, flag, cnt);
}

// Round 11
// 14.468 us; speedup vs baseline: 2.3768x; 2.3768x over previous
//
#include <hip/hip_runtime.h>
#include <math.h>

#define NROWS 8192
#define DD    64
#define K1B   256
#define K1T   512
#define K1W   8
#define K1RPW (NROWS / (K1B * K1W))    // 4 rows per wave
#define K2B   256
#define K2T   512

// Star-graph GAT (identities validated r1-r10, absmax 3.9e-3):
//   e[i][j] = h1[i] + h2[j]; h1 cancels in row softmax -> s[j] = h[j]·A[:64]
//   row i>0: masked softmax = 2-way {j=0, j=i};  row 0: full softmax via partials
//   exp without max-subtraction safe in fp32 (|s| <~ 8)
// R10 post-mortem: in-kernel device barrier ~20us regardless of spin idiom ->
// revert to 2 dispatches. K1 does ALL per-row heavy work for BOTH layers
// (layer-1 rows + e2[r] + layer-2 row-0 partials, all from registers);
// K2 is a pure stream: combine -> h0, then 1 float4 load + mix + store per
// thread. No atomics, no counters, fixed-order reductions -> deterministic.

__device__ __forceinline__ float wsum64(float v) {
    #pragma unroll
    for (int o = 32; o; o >>= 1) v += __shfl_xor(v, o);
    return v;
}

// K1: per-row scores/exp for layer 1, layer-1 rows -> out (r>=1), e2[r],
// block partials for layer-1 row 0 (part1,z1) and layer-2 row 0 (part2,z2;
// excluding the r=0 term, which K2 adds as e2_0*h0).
__global__ __launch_bounds__(K1T) void gat_k1(
    const float* __restrict__ x, const float* __restrict__ A1,
    const float* __restrict__ A2, float* __restrict__ out,
    float* __restrict__ e2, float* __restrict__ part1, float* __restrict__ z1,
    float* __restrict__ part2, float* __restrict__ z2)
{
    const int lane = threadIdx.x & 63;
    const int wl   = threadIdx.x >> 6;
    const int r0   = (blockIdx.x * K1W + wl) * K1RPW;

    __shared__ float sa[K1W][DD], sb[K1W][DD];
    __shared__ float sza[K1W], szb[K1W];

    float w1 = A1[lane], w2 = A2[lane];
    float x0 = x[lane];                    // row 0, lane-distributed
    float e10 = expf(wsum64(x0 * w1));

    float a1 = 0.f, q1 = 0.f, a2 = 0.f, q2 = 0.f;
    #pragma unroll
    for (int k = 0; k < K1RPW; ++k) {
        int r = r0 + k;
        float hv = x[r * DD + lane];
        float e1 = expf(wsum64(hv * w1));
        a1 += e1 * hv;                     // layer-1 row-0 numerator (incl. r=0)
        q1 += e1;
        if (r != 0) {
            float o1 = (e10 * x0 + e1 * hv) / (e10 + e1);  // layer-1 row r
            out[r * DD + lane] = o1;
            float e2r = expf(wsum64(o1 * w2));             // layer-2 score exp
            if (lane == 0) e2[r] = e2r;
            a2 += e2r * o1;                // layer-2 row-0 numerator (excl. r=0)
            q2 += e2r;
        }
    }
    sa[wl][lane] = a1; sb[wl][lane] = a2;
    if (lane == 0) { sza[wl] = q1; szb[wl] = q2; }
    __syncthreads();
    if (wl == 0) {
        float p1 = 0.f, p2 = 0.f;
        #pragma unroll
        for (int j = 0; j < K1W; ++j) { p1 += sa[j][lane]; p2 += sb[j][lane]; }
        part1[blockIdx.x * DD + lane] = p1;
        part2[blockIdx.x * DD + lane] = p2;
        if (lane == 0) {
            float u1 = 0.f, u2 = 0.f;
            #pragma unroll
            for (int j = 0; j < K1W; ++j) { u1 += sza[j]; u2 += szb[j]; }
            z1[blockIdx.x] = u1; z2[blockIdx.x] = u2;
        }
    }
}

// K2: thread -> (row = bid*32 + tid/16, colgroup = tid%16), 1 float4 each.
// Combine part1 -> h0 + e2_0 (all blocks, fixed order); block 0 also combines
// part2 -> final out[0]. Main: out[r] = (e2_0*h0 + e2_r*h1_r)/(e2_0+e2_r).
__global__ __launch_bounds__(K2T) void gat_k2(
    const float* __restrict__ A2, float* __restrict__ out,
    const float* __restrict__ e2,
    const float* __restrict__ part1, const float* __restrict__ z1,
    const float* __restrict__ part2, const float* __restrict__ z2)
{
    const int tid  = threadIdx.x;
    const int lane = tid & 63;
    const int wl   = tid >> 6;
    const int cg   = lane & 15;
    const int grp  = lane >> 4;            // 0..3
    const int row  = blockIdx.x * 32 + (tid >> 4);

    // issue own-row loads first (latency hides under combine)
    float4 hv4 = *(const float4*)(out + row * DD + cg * 4);  // row 0: poison, unused
    float  er  = e2[row];                                    // broadcast per 16 thr

    __shared__ float4 swa[8][16];
    __shared__ float  szw[8];
    __shared__ float4 h0sh[16];
    __shared__ float  e20sh;
    __shared__ float4 out0sh[16];

    // ---- combine1: 256 part1 rows; wave w covers p in [w*32, w*32+32) ----
    {
        const float4* P = (const float4*)part1;
        int p0 = wl * 32 + grp;
        float4 s = make_float4(0.f, 0.f, 0.f, 0.f);
        float zs = 0.f;
        #pragma unroll
        for (int i = 0; i < 8; ++i) {
            float4 v = P[(p0 + i * 4) * 16 + cg];
            s.x += v.x; s.y += v.y; s.z += v.z; s.w += v.w;
            zs += z1[p0 + i * 4];
        }
        #pragma unroll
        for (int o = 16; o <= 32; o <<= 1) {
            s.x += __shfl_xor(s.x, o); s.y += __shfl_xor(s.y, o);
            s.z += __shfl_xor(s.z, o); s.w += __shfl_xor(s.w, o);
            zs  += __shfl_xor(zs, o);
        }
        if (lane < 16) swa[wl][lane] = s;
        if (lane == 0) szw[wl] = zs;
    }
    __syncthreads();
    if (wl == 0 && lane < 16) {
        float4 h = swa[0][lane];
        #pragma unroll
        for (int j = 1; j < 8; ++j) {
            float4 v = swa[j][lane];
            h.x += v.x; h.y += v.y; h.z += v.z; h.w += v.w;
        }
        float Z = 0.f;
        #pragma unroll
        for (int j = 0; j < 8; ++j) Z += szw[j];
        float inv = 1.f / Z;
        float4 h0 = make_float4(h.x * inv, h.y * inv, h.z * inv, h.w * inv);
        h0sh[lane] = h0;
        float4 a24 = ((const float4*)A2)[lane];
        float d = h0.x * a24.x + h0.y * a24.y + h0.z * a24.z + h0.w * a24.w;
        #pragma unroll
        for (int o = 8; o; o >>= 1) d += __shfl_xor(d, o);
        if (lane == 0) e20sh = expf(d);    // e2_0 = exp(h0 · A2[:64])
    }
    __syncthreads();

    // ---- combine2 (block 0 only): final out[0] ----
    if (blockIdx.x == 0) {
        const float4* P = (const float4*)part2;
        int p0 = wl * 32 + grp;
        float4 s = make_float4(0.f, 0.f, 0.f, 0.f);
        float zs = 0.f;
        #pragma unroll
        for (int i = 0; i < 8; ++i) {
            float4 v = P[(p0 + i * 4) * 16 + cg];
            s.x += v.x; s.y += v.y; s.z += v.z; s.w += v.w;
            zs += z2[p0 + i * 4];
        }
        #pragma unroll
        for (int o = 16; o <= 32; o <<= 1) {
            s.x += __shfl_xor(s.x, o); s.y += __shfl_xor(s.y, o);
            s.z += __shfl_xor(s.z, o); s.w += __shfl_xor(s.w, o);
            zs  += __shfl_xor(zs, o);
        }
        if (lane < 16) swa[wl][lane] = s;  // reuse (prior reads done pre-sync)
        if (lane == 0) szw[wl] = zs;
    }
    __syncthreads();
    if (blockIdx.x == 0 && wl == 0 && lane < 16) {
        float4 p = swa[0][lane];
        #pragma unroll
        for (int j = 1; j < 8; ++j) {
            float4 v = swa[j][lane];
            p.x += v.x; p.y += v.y; p.z += v.z; p.w += v.w;
        }
        float Zb = 0.f;
        #pragma unroll
        for (int j = 0; j < 8; ++j) Zb += szw[j];
        float e20 = e20sh;
        float4 h0 = h0sh[lane];
        float inv = 1.f / (Zb + e20);      // add the r=0 term e2_0*h0 here
        out0sh[lane] = make_float4((p.x + e20 * h0.x) * inv,
                                   (p.y + e20 * h0.y) * inv,
                                   (p.z + e20 * h0.z) * inv,
                                   (p.w + e20 * h0.w) * inv);
    }
    __syncthreads();

    // ---- main: pure mix, 1 float4 per thread ----
    float  e20 = e20sh;
    float4 h0  = h0sh[cg];
    float4 o4;
    if (row == 0) {
        o4 = out0sh[cg];
    } else {
        float inv = 1.f / (e20 + er);
        o4 = make_float4((e20 * h0.x + er * hv4.x) * inv,
                         (e20 * h0.y + er * hv4.y) * inv,
                         (e20 * h0.z + er * hv4.z) * inv,
                         (e20 * h0.w + er * hv4.w) * inv);
    }
    *(float4*)(out + row * DD + cg * 4) = o4;
}

extern "C" void kernel_launch(void* const* d_in, const int* in_sizes, int n_in,
                              void* d_out, int out_size, void* d_ws, size_t ws_size,
                              hipStream_t stream)
{
    const float* x  = (const float*)d_in[0];
    const float* A1 = (const float*)d_in[1];
    const float* A2 = (const float*)d_in[2];
    float* out = (float*)d_out;
    float* ws  = (float*)d_ws;

    float* part1 = ws;                         // 256*64
    float* z1    = part1 + K1B * DD;           // 256
    float* part2 = z1 + K1B;                   // 256*64
    float* z2    = part2 + K1B * DD;           // 256
    float* e2    = z2 + K1B;                   // 8192

    gat_k1<<<K1B, K1T, 0, stream>>>(x, A1, A2, out, e2, part1, z1, part2, z2);
    gat_k2<<<K2B, K2T, 0, stream>>>(A2, out, e2, part1, z1, part2, z2);
}

// Round 12
// 14.194 us; speedup vs baseline: 2.4226x; 1.0193x over previous
//
#include <hip/hip_runtime.h>
#include <math.h>

#define NROWS 8192
#define DD    64
#define K1B   128
#define K1T   512
#define K1W   8
#define K1RPW (NROWS / (K1B * K1W))    // 8 rows per wave
#define K2B   256
#define K2T   512

// Star-graph GAT (identities validated r1-r11, absmax 3.9e-3):
//   e[i][j] = h1[i] + h2[j]; h1 cancels in row softmax -> s[j] = h[j]·A[:64]
//   row i>0: masked softmax = 2-way {j=0, j=i};  row 0: full softmax via partials
//   exp without max-subtraction safe in fp32 (|s| <~ 8)
// R11 post-mortem: ~11.5us of 14.5 is the 2-dispatch replay floor; in-kernel
// device barriers cost ~20-25us (R2/R8/R9/R10 - platform constant). This round
// removes the h1/e2 HBM round-trip: K1 writes ONLY partials (33KB); K2
// recomputes h1/e2 from x (L3-hot) in registers. No atomics, no counters,
// fixed-order reductions -> deterministic and poison-proof.

__device__ __forceinline__ float wsum64(float v) {
    #pragma unroll
    for (int o = 32; o; o >>= 1) v += __shfl_xor(v, o);
    return v;
}

// K1: per-row e1/h1/e2 in registers; block partials for layer-1 row 0
// (part1,z1) and layer-2 row 0 (part2,z2; excluding r=0 term added in K2).
__global__ __launch_bounds__(K1T) void gat_k1(
    const float* __restrict__ x, const float* __restrict__ A1,
    const float* __restrict__ A2,
    float* __restrict__ part1, float* __restrict__ z1,
    float* __restrict__ part2, float* __restrict__ z2)
{
    const int lane = threadIdx.x & 63;
    const int wl   = threadIdx.x >> 6;
    const int r0   = (blockIdx.x * K1W + wl) * K1RPW;

    __shared__ float sa[K1W][DD], sb[K1W][DD];
    __shared__ float sza[K1W], szb[K1W];

    float w1 = A1[lane], w2 = A2[lane];
    float x0 = x[lane];                    // row 0, lane-distributed
    float e10 = expf(wsum64(x0 * w1));

    float a1 = 0.f, q1 = 0.f, a2 = 0.f, q2 = 0.f;
    #pragma unroll
    for (int k = 0; k < K1RPW; ++k) {
        int r = r0 + k;
        float hv = x[r * DD + lane];
        float e1 = expf(wsum64(hv * w1));
        a1 += e1 * hv;                     // layer-1 row-0 numerator (incl. r=0)
        q1 += e1;
        if (r != 0) {
            float o1 = (e10 * x0 + e1 * hv) / (e10 + e1);  // layer-1 row (regs only)
            float e2r = expf(wsum64(o1 * w2));
            a2 += e2r * o1;                // layer-2 row-0 numerator (excl. r=0)
            q2 += e2r;
        }
    }
    sa[wl][lane] = a1; sb[wl][lane] = a2;
    if (lane == 0) { sza[wl] = q1; szb[wl] = q2; }
    __syncthreads();
    if (wl == 0) {
        float p1 = 0.f, p2 = 0.f;
        #pragma unroll
        for (int j = 0; j < K1W; ++j) { p1 += sa[j][lane]; p2 += sb[j][lane]; }
        part1[blockIdx.x * DD + lane] = p1;
        part2[blockIdx.x * DD + lane] = p2;
        if (lane == 0) {
            float u1 = 0.f, u2 = 0.f;
            #pragma unroll
            for (int j = 0; j < K1W; ++j) { u1 += sza[j]; u2 += szb[j]; }
            z1[blockIdx.x] = u1; z2[blockIdx.x] = u2;
        }
    }
}

// K2: thread -> (row = bid*32 + tid/16, colgroup = tid%16), 1 float4 each.
// Combine 128 part1 rows -> h0,e20 (all blocks, fixed order); block 0 also
// combines part2 -> final out[0]. Rows r>0: recompute e1,h1,e2 from x and mix.
__global__ __launch_bounds__(K2T) void gat_k2(
    const float* __restrict__ x, const float* __restrict__ A1,
    const float* __restrict__ A2, float* __restrict__ out,
    const float* __restrict__ part1, const float* __restrict__ z1,
    const float* __restrict__ part2, const float* __restrict__ z2)
{
    const int tid  = threadIdx.x;
    const int lane = tid & 63;
    const int wl   = tid >> 6;
    const int cg   = lane & 15;
    const int grp  = lane >> 4;            // 0..3
    const int row  = blockIdx.x * 32 + (tid >> 4);

    // issue own-row + row-0 loads first (latency hides under combine)
    float4 xrf = *(const float4*)(x + row * DD + cg * 4);
    float4 x0f = ((const float4*)x)[cg];
    float4 w1f = ((const float4*)A1)[cg];
    float4 w2f = ((const float4*)A2)[cg];

    __shared__ float4 swa[8][16];
    __shared__ float  szw[8];
    __shared__ float4 h0sh[16];
    __shared__ float  e20sh;
    __shared__ float4 out0sh[16];

    // ---- combine1: 128 part1 rows; wave w covers p in [w*16, w*16+16) ----
    {
        const float4* P = (const float4*)part1;
        int p0 = wl * 16 + grp;
        float4 s = make_float4(0.f, 0.f, 0.f, 0.f);
        float zs = 0.f;
        #pragma unroll
        for (int i = 0; i < 4; ++i) {
            float4 v = P[(p0 + i * 4) * 16 + cg];
            s.x += v.x; s.y += v.y; s.z += v.z; s.w += v.w;
            zs += z1[p0 + i * 4];
        }
        #pragma unroll
        for (int o = 16; o <= 32; o <<= 1) {
            s.x += __shfl_xor(s.x, o); s.y += __shfl_xor(s.y, o);
            s.z += __shfl_xor(s.z, o); s.w += __shfl_xor(s.w, o);
            zs  += __shfl_xor(zs, o);
        }
        if (lane < 16) swa[wl][lane] = s;
        if (lane == 0) szw[wl] = zs;
    }
    __syncthreads();
    if (wl == 0 && lane < 16) {
        float4 h = swa[0][lane];
        #pragma unroll
        for (int j = 1; j < 8; ++j) {
            float4 v = swa[j][lane];
            h.x += v.x; h.y += v.y; h.z += v.z; h.w += v.w;
        }
        float Z = 0.f;
        #pragma unroll
        for (int j = 0; j < 8; ++j) Z += szw[j];
        float inv = 1.f / Z;
        float4 h0 = make_float4(h.x * inv, h.y * inv, h.z * inv, h.w * inv);
        h0sh[lane] = h0;
        float4 a24 = ((const float4*)A2)[lane];
        float d = h0.x * a24.x + h0.y * a24.y + h0.z * a24.z + h0.w * a24.w;
        #pragma unroll
        for (int o = 8; o; o >>= 1) d += __shfl_xor(d, o);
        if (lane == 0) e20sh = expf(d);    // e2_0 = exp(h0 · A2[:64])
    }
    __syncthreads();

    // ---- combine2 (block 0 only): final out[0] ----
    if (blockIdx.x == 0) {
        const float4* P = (const float4*)part2;
        int p0 = wl * 16 + grp;
        float4 s = make_float4(0.f, 0.f, 0.f, 0.f);
        float zs = 0.f;
        #pragma unroll
        for (int i = 0; i < 4; ++i) {
            float4 v = P[(p0 + i * 4) * 16 + cg];
            s.x += v.x; s.y += v.y; s.z += v.z; s.w += v.w;
            zs += z2[p0 + i * 4];
        }
        #pragma unroll
        for (int o = 16; o <= 32; o <<= 1) {
            s.x += __shfl_xor(s.x, o); s.y += __shfl_xor(s.y, o);
            s.z += __shfl_xor(s.z, o); s.w += __shfl_xor(s.w, o);
            zs  += __shfl_xor(zs, o);
        }
        if (lane < 16) swa[wl][lane] = s;  // reuse (prior reads done pre-sync)
        if (lane == 0) szw[wl] = zs;
    }
    __syncthreads();
    if (blockIdx.x == 0 && wl == 0 && lane < 16) {
        float4 p = swa[0][lane];
        #pragma unroll
        for (int j = 1; j < 8; ++j) {
            float4 v = swa[j][lane];
            p.x += v.x; p.y += v.y; p.z += v.z; p.w += v.w;
        }
        float Zb = 0.f;
        #pragma unroll
        for (int j = 0; j < 8; ++j) Zb += szw[j];
        float e20 = e20sh;
        float4 h0 = h0sh[lane];
        float inv = 1.f / (Zb + e20);      // add the r=0 term e2_0*h0 here
        out0sh[lane] = make_float4((p.x + e20 * h0.x) * inv,
                                   (p.y + e20 * h0.y) * inv,
                                   (p.z + e20 * h0.z) * inv,
                                   (p.w + e20 * h0.w) * inv);
    }
    __syncthreads();

    // ---- main: recompute e1,h1,e2 in registers, mix, store ----
    float  e20 = e20sh;
    float4 h0  = h0sh[cg];
    float4 o4;
    if (row == 0) {
        o4 = out0sh[cg];
    } else {
        // s0/sr: 16-lane dot-reduce (xor 1,2,4,8 stays within the 16-lane group)
        float s0 = x0f.x * w1f.x + x0f.y * w1f.y + x0f.z * w1f.z + x0f.w * w1f.w;
        float sr = xrf.x * w1f.x + xrf.y * w1f.y + xrf.z * w1f.z + xrf.w * w1f.w;
        #pragma unroll
        for (int o = 8; o; o >>= 1) { s0 += __shfl_xor(s0, o); sr += __shfl_xor(sr, o); }
        float e10 = expf(s0), e1 = expf(sr);
        float i1 = 1.f / (e10 + e1);
        float4 h1 = make_float4((e10 * x0f.x + e1 * xrf.x) * i1,
                                (e10 * x0f.y + e1 * xrf.y) * i1,
                                (e10 * x0f.z + e1 * xrf.z) * i1,
                                (e10 * x0f.w + e1 * xrf.w) * i1);
        float tr = h1.x * w2f.x + h1.y * w2f.y + h1.z * w2f.z + h1.w * w2f.w;
        #pragma unroll
        for (int o = 8; o; o >>= 1) tr += __shfl_xor(tr, o);
        float e2 = expf(tr);
        float i2 = 1.f / (e20 + e2);
        o4 = make_float4((e20 * h0.x + e2 * h1.x) * i2,
                         (e20 * h0.y + e2 * h1.y) * i2,
                         (e20 * h0.z + e2 * h1.z) * i2,
                         (e20 * h0.w + e2 * h1.w) * i2);
    }
    *(float4*)(out + row * DD + cg * 4) = o4;
}

extern "C" void kernel_launch(void* const* d_in, const int* in_sizes, int n_in,
                              void* d_out, int out_size, void* d_ws, size_t ws_size,
                              hipStream_t stream)
{
    const float* x  = (const float*)d_in[0];
    const float* A1 = (const float*)d_in[1];
    const float* A2 = (const float*)d_in[2];
    float* out = (float*)d_out;
    float* ws  = (float*)d_ws;

    float* part1 = ws;                         // 128*64
    float* z1    = part1 + K1B * DD;           // 128
    float* part2 = z1 + K1B;                   // 128*64
    float* z2    = part2 + K1B * DD;           // 128

    gat_k1<<<K1B, K1T, 0, stream>>>(x, A1, A2, part1, z1, part2, z2);
    gat_k2<<<K2B, K2T, 0, stream>>>(x, A1, A2, out, part1, z1, part2, z2);
}

// Round 14
// 13.969 us; speedup vs baseline: 2.4617x; 1.0161x over previous
//
#include <hip/hip_runtime.h>
#include <math.h>

#define NROWS 8192
#define DD    64
#define K1B   128
#define K1T   512
#define K1W   8
#define K1RPW (NROWS / (K1B * K1W))    // 8 rows per wave
#define K2B   256
#define K2T   512

// Star-graph GAT (identities validated r1-r12, absmax 3.9e-3):
//   e[i][j] = h1[i] + h2[j]; h1 cancels in row softmax -> s[j] = h[j]·A[:64]
//   row i>0: masked softmax = 2-way {j=0, j=i};  row 0: full softmax via partials
//   exp without max-subtraction safe in fp32 (|s| <~ 8)
// FINAL STRUCTURE (r13 post-mortem): the global reduction (h1[0] feeds every
// output row) forces either a device-wide coherence event (~20us: R2 coop,
// R8 acquire-spin, R9 relaxed-spin, R10 RMW-spin) or a kernel boundary (~6us).
// Fence-free NT handoff (R13) reads stale data -> single-dispatch is dead.
// 2 dispatches x ~6us replay overhead + ~2us work = ~14us structural floor.
// K1 writes ONLY partials (33KB); K2 recomputes h1/e2 from x (L3-hot) in
// registers. No atomics, no counters, fixed-order -> deterministic.

__device__ __forceinline__ float wsum64(float v) {
    #pragma unroll
    for (int o = 32; o; o >>= 1) v += __shfl_xor(v, o);
    return v;
}

// K1: per-row e1/h1/e2 in registers; block partials for layer-1 row 0
// (part1,z1) and layer-2 row 0 (part2,z2; excluding r=0 term added in K2).
__global__ __launch_bounds__(K1T) void gat_k1(
    const float* __restrict__ x, const float* __restrict__ A1,
    const float* __restrict__ A2,
    float* __restrict__ part1, float* __restrict__ z1,
    float* __restrict__ part2, float* __restrict__ z2)
{
    const int lane = threadIdx.x & 63;
    const int wl   = threadIdx.x >> 6;
    const int r0   = (blockIdx.x * K1W + wl) * K1RPW;

    __shared__ float sa[K1W][DD], sb[K1W][DD];
    __shared__ float sza[K1W], szb[K1W];

    float w1 = A1[lane], w2 = A2[lane];
    float x0 = x[lane];                    // row 0, lane-distributed
    float e10 = expf(wsum64(x0 * w1));

    float a1 = 0.f, q1 = 0.f, a2 = 0.f, q2 = 0.f;
    #pragma unroll
    for (int k = 0; k < K1RPW; ++k) {
        int r = r0 + k;
        float hv = x[r * DD + lane];
        float e1 = expf(wsum64(hv * w1));
        a1 += e1 * hv;                     // layer-1 row-0 numerator (incl. r=0)
        q1 += e1;
        if (r != 0) {
            float o1 = (e10 * x0 + e1 * hv) / (e10 + e1);  // layer-1 row (regs only)
            float e2r = expf(wsum64(o1 * w2));
            a2 += e2r * o1;                // layer-2 row-0 numerator (excl. r=0)
            q2 += e2r;
        }
    }
    sa[wl][lane] = a1; sb[wl][lane] = a2;
    if (lane == 0) { sza[wl] = q1; szb[wl] = q2; }
    __syncthreads();
    if (wl == 0) {
        float p1 = 0.f, p2 = 0.f;
        #pragma unroll
        for (int j = 0; j < K1W; ++j) { p1 += sa[j][lane]; p2 += sb[j][lane]; }
        part1[blockIdx.x * DD + lane] = p1;
        part2[blockIdx.x * DD + lane] = p2;
        if (lane == 0) {
            float u1 = 0.f, u2 = 0.f;
            #pragma unroll
            for (int j = 0; j < K1W; ++j) { u1 += sza[j]; u2 += szb[j]; }
            z1[blockIdx.x] = u1; z2[blockIdx.x] = u2;
        }
    }
}

// K2: thread -> (row = bid*32 + tid/16, colgroup = tid%16), 1 float4 each.
// Combine 128 part1 rows -> h0,e20 (all blocks, fixed order); block 0 also
// combines part2 -> final out[0]. Rows r>0: recompute e1,h1,e2 from x and mix.
__global__ __launch_bounds__(K2T) void gat_k2(
    const float* __restrict__ x, const float* __restrict__ A1,
    const float* __restrict__ A2, float* __restrict__ out,
    const float* __restrict__ part1, const float* __restrict__ z1,
    const float* __restrict__ part2, const float* __restrict__ z2)
{
    const int tid  = threadIdx.x;
    const int lane = tid & 63;
    const int wl   = tid >> 6;
    const int cg   = lane & 15;
    const int grp  = lane >> 4;            // 0..3
    const int row  = blockIdx.x * 32 + (tid >> 4);

    // issue own-row + row-0 loads first (latency hides under combine)
    float4 xrf = *(const float4*)(x + row * DD + cg * 4);
    float4 x0f = ((const float4*)x)[cg];
    float4 w1f = ((const float4*)A1)[cg];
    float4 w2f = ((const float4*)A2)[cg];

    __shared__ float4 swa[8][16];
    __shared__ float  szw[8];
    __shared__ float4 h0sh[16];
    __shared__ float  e20sh;
    __shared__ float4 out0sh[16];

    // ---- combine1: 128 part1 rows; wave w covers p in [w*16, w*16+16) ----
    {
        const float4* P = (const float4*)part1;
        int p0 = wl * 16 + grp;
        float4 s = make_float4(0.f, 0.f, 0.f, 0.f);
        float zs = 0.f;
        #pragma unroll
        for (int i = 0; i < 4; ++i) {
            float4 v = P[(p0 + i * 4) * 16 + cg];
            s.x += v.x; s.y += v.y; s.z += v.z; s.w += v.w;
            zs += z1[p0 + i * 4];
        }
        #pragma unroll
        for (int o = 16; o <= 32; o <<= 1) {
            s.x += __shfl_xor(s.x, o); s.y += __shfl_xor(s.y, o);
            s.z += __shfl_xor(s.z, o); s.w += __shfl_xor(s.w, o);
            zs  += __shfl_xor(zs, o);
        }
        if (lane < 16) swa[wl][lane] = s;
        if (lane == 0) szw[wl] = zs;
    }
    __syncthreads();
    if (wl == 0 && lane < 16) {
        float4 h = swa[0][lane];
        #pragma unroll
        for (int j = 1; j < 8; ++j) {
            float4 v = swa[j][lane];
            h.x += v.x; h.y += v.y; h.z += v.z; h.w += v.w;
        }
        float Z = 0.f;
        #pragma unroll
        for (int j = 0; j < 8; ++j) Z += szw[j];
        float inv = 1.f / Z;
        float4 h0 = make_float4(h.x * inv, h.y * inv, h.z * inv, h.w * inv);
        h0sh[lane] = h0;
        float4 a24 = ((const float4*)A2)[lane];
        float d = h0.x * a24.x + h0.y * a24.y + h0.z * a24.z + h0.w * a24.w;
        #pragma unroll
        for (int o = 8; o; o >>= 1) d += __shfl_xor(d, o);
        if (lane == 0) e20sh = expf(d);    // e2_0 = exp(h0 · A2[:64])
    }
    __syncthreads();

    // ---- combine2 (block 0 only): final out[0] ----
    if (blockIdx.x == 0) {
        const float4* P = (const float4*)part2;
        int p0 = wl * 16 + grp;
        float4 s = make_float4(0.f, 0.f, 0.f, 0.f);
        float zs = 0.f;
        #pragma unroll
        for (int i = 0; i < 4; ++i) {
            float4 v = P[(p0 + i * 4) * 16 + cg];
            s.x += v.x; s.y += v.y; s.z += v.z; s.w += v.w;
            zs += z2[p0 + i * 4];
        }
        #pragma unroll
        for (int o = 16; o <= 32; o <<= 1) {
            s.x += __shfl_xor(s.x, o); s.y += __shfl_xor(s.y, o);
            s.z += __shfl_xor(s.z, o); s.w += __shfl_xor(s.w, o);
            zs  += __shfl_xor(zs, o);
        }
        if (lane < 16) swa[wl][lane] = s;  // reuse (prior reads done pre-sync)
        if (lane == 0) szw[wl] = zs;
    }
    __syncthreads();
    if (blockIdx.x == 0 && wl == 0 && lane < 16) {
        float4 p = swa[0][lane];
        #pragma unroll
        for (int j = 1; j < 8; ++j) {
            float4 v = swa[j][lane];
            p.x += v.x; p.y += v.y; p.z += v.z; p.w += v.w;
        }
        float Zb = 0.f;
        #pragma unroll
        for (int j = 0; j < 8; ++j) Zb += szw[j];
        float e20 = e20sh;
        float4 h0 = h0sh[lane];
        float inv = 1.f / (Zb + e20);      // add the r=0 term e2_0*h0 here
        out0sh[lane] = make_float4((p.x + e20 * h0.x) * inv,
                                   (p.y + e20 * h0.y) * inv,
                                   (p.z + e20 * h0.z) * inv,
                                   (p.w + e20 * h0.w) * inv);
    }
    __syncthreads();

    // ---- main: recompute e1,h1,e2 in registers, mix, store ----
    float  e20 = e20sh;
    float4 h0  = h0sh[cg];
    float4 o4;
    if (row == 0) {
        o4 = out0sh[cg];
    } else {
        // s0/sr: 16-lane dot-reduce (xor 1,2,4,8 stays within the 16-lane group)
        float s0 = x0f.x * w1f.x + x0f.y * w1f.y + x0f.z * w1f.z + x0f.w * w1f.w;
        float sr = xrf.x * w1f.x + xrf.y * w1f.y + xrf.z * w1f.z + xrf.w * w1f.w;
        #pragma unroll
        for (int o = 8; o; o >>= 1) { s0 += __shfl_xor(s0, o); sr += __shfl_xor(sr, o); }
        float e10 = expf(s0), e1 = expf(sr);
        float i1 = 1.f / (e10 + e1);
        float4 h1 = make_float4((e10 * x0f.x + e1 * xrf.x) * i1,
                                (e10 * x0f.y + e1 * xrf.y) * i1,
                                (e10 * x0f.z + e1 * xrf.z) * i1,
                                (e10 * x0f.w + e1 * xrf.w) * i1);
        float tr = h1.x * w2f.x + h1.y * w2f.y + h1.z * w2f.z + h1.w * w2f.w;
        #pragma unroll
        for (int o = 8; o; o >>= 1) tr += __shfl_xor(tr, o);
        float e2 = expf(tr);
        float i2 = 1.f / (e20 + e2);
        o4 = make_float4((e20 * h0.x + e2 * h1.x) * i2,
                         (e20 * h0.y + e2 * h1.y) * i2,
                         (e20 * h0.z + e2 * h1.z) * i2,
                         (e20 * h0.w + e2 * h1.w) * i2);
    }
    *(float4*)(out + row * DD + cg * 4) = o4;
}

extern "C" void kernel_launch(void* const* d_in, const int* in_sizes, int n_in,
                              void* d_out, int out_size, void* d_ws, size_t ws_size,
                              hipStream_t stream)
{
    const float* x  = (const float*)d_in[0];
    const float* A1 = (const float*)d_in[1];
    const float* A2 = (const float*)d_in[2];
    float* out = (float*)d_out;
    float* ws  = (float*)d_ws;

    float* part1 = ws;                         // 128*64
    float* z1    = part1 + K1B * DD;           // 128
    float* part2 = z1 + K1B;                   // 128*64
    float* z2    = part2 + K1B * DD;           // 128

    gat_k1<<<K1B, K1T, 0, stream>>>(x, A1, A2, part1, z1, part2, z2);
    gat_k2<<<K2B, K2T, 0, stream>>>(x, A1, A2, out, part1, z1, part2, z2);
}